// Round 13
// baseline (376.977 us; speedup 1.0000x reference)
//
#include <hip/hip_runtime.h>
#include <hip/hip_bf16.h>
#include <cstdint>
#include <cstddef>

#define SEQ 256
#define WDIM 256
#define CDIM 512
#define NHEAD 8
#define HD 64
#define NTOK (SEQ*WDIM)
#define NTT 8   // K=512 / BK=64 (non-persistent gemm256, k_proj)

typedef __attribute__((ext_vector_type(8))) short bf16x8;
typedef __attribute__((ext_vector_type(4))) float f32x4;

static __device__ __forceinline__ unsigned short f2bf(float f) {
  __hip_bfloat16 h = __float2bfloat16(f);
  return *reinterpret_cast<unsigned short*>(&h);
}

// ---------------- kernel 0: fp32 -> bf16 conversion (x + weights) ----------------
__global__ void k_convert(const float* __restrict__ x,
                          const float* __restrict__ wqkv,
                          const float* __restrict__ wproj,
                          unsigned short* __restrict__ xb,
                          unsigned short* __restrict__ wqb,
                          unsigned short* __restrict__ wpb) {
  const int NX = NTOK*CDIM/4, NQ = 3*CDIM*CDIM/4, NP = CDIM*CDIM/4;
  const int total = NX + NQ + NP;
  for (int i = blockIdx.x*blockDim.x + threadIdx.x; i < total; i += gridDim.x*blockDim.x) {
    const float4* s; unsigned short* d; int j;
    if (i < NX)           { s = (const float4*)x;     d = xb;  j = i; }
    else if (i < NX+NQ)   { s = (const float4*)wqkv;  d = wqb; j = i-NX; }
    else                  { s = (const float4*)wproj; d = wpb; j = i-NX-NQ; }
    float4 f = s[j];
    ushort4 o;
    o.x = f2bf(f.x); o.y = f2bf(f.y); o.z = f2bf(f.z); o.w = f2bf(f.w);
    ((ushort4*)d)[j] = o;
  }
}

// ---------------- kernel 0b: RoPE cos/sin table [256][32] ----------------
__global__ void k_rope(float2* __restrict__ tab) {
  int i = blockIdx.x*blockDim.x + threadIdx.x;
  if (i >= SEQ*32) return;
  int h = i >> 5, j = i & 31;
  float freq = expf(-12.0f + 12.0f*(float)j/31.0f);
  float ang = ((float)h/255.0f) * freq * 256.0f;
  tab[i] = make_float2(cosf(ang), sinf(ang));
}

// ================= shared GEMM macros =================
// LDS: L[buf][A=0/B=1][half][128x64 bf16], granule g of row r stored at g^(r&7) (T2).

#define LDA_(dst, m_, kk_)                                                                 \
  { int r_ = (m_)*16 + li;                                                                 \
    dst = *(const bf16x8*)((const char*)&L[buf][0][wr][0] + r_*128 + (((((kk_)*4)+lg) ^ (r_ & 7))<<4)); }
#define LDB_(dst, n_, kk_)                                                                 \
  { int r_ = (wc & 1)*64 + (n_)*16 + li;                                                   \
    dst = *(const bf16x8*)((const char*)&L[buf][1][wc>>1][0] + r_*128 + (((((kk_)*4)+lg) ^ (r_ & 7))<<4)); }

#define PH_SYNC                                            \
  __builtin_amdgcn_s_barrier();                            \
  asm volatile("s_waitcnt lgkmcnt(0)" ::: "memory");       \
  __builtin_amdgcn_sched_barrier(0);

#define MFMA16(afr, bfr, mo)                                                               \
  __builtin_amdgcn_s_setprio(1);                                                          \
  _Pragma("unroll")                                                                        \
  for (int m = 0; m < 4; ++m)                                                              \
    _Pragma("unroll")                                                                      \
    for (int n = 0; n < 4; ++n)                                                            \
      acc[m+(mo)][n] = __builtin_amdgcn_mfma_f32_16x16x32_bf16(afr[m], bfr[n], acc[m+(mo)][n], 0, 0, 0); \
  __builtin_amdgcn_s_setprio(0);

// ---------------- non-persistent 256x256 4-phase core (k_proj; R7/R9-proven) ----------------
#define STAGE_G(tau_, part_)                                                              \
  if ((tau_) < NTT) {                                                                     \
    const int buf_ = (tau_) & 1;                                                          \
    const int ab_ = (part_) >> 1, hh_ = (part_) & 1;                                      \
    const unsigned short* src_ = ab_ ? B : A;                                             \
    const int row0_ = (ab_ ? rowB0 : rowA0) + hh_*128;                                    \
    _Pragma("unroll")                                                                     \
    for (int c_ = 0; c_ < 2; ++c_) {                                                      \
      int G_ = wid*128 + c_*64 + lane;                                                    \
      int r_ = G_ >> 3, g_ = G_ & 7;                                                      \
      int gsw_ = g_ ^ (r_ & 7);                                                           \
      __builtin_amdgcn_global_load_lds(                                                   \
        (const __attribute__((address_space(1))) unsigned int*)                           \
          ((const char*)src_ + (size_t)(row0_ + r_)*1024 + (size_t)(tau_)*128 + gsw_*16), \
        (__attribute__((address_space(3))) unsigned int*)                                 \
          ((char*)&L[buf_][ab_][hh_][0] + G_*16),                                         \
        16, 0, 0);                                                                        \
    }                                                                                     \
  }

__device__ __forceinline__ void gemm256(const unsigned short* __restrict__ A,
                                        const unsigned short* __restrict__ B,
                                        int rowA0, int rowB0,
                                        unsigned short (&L)[2][2][2][128*64],
                                        f32x4 (&acc)[8][4]) {
  const int tid = threadIdx.x;
  const int lane = tid & 63, wid = tid >> 6;
  const int wr = wid >> 2, wc = wid & 3;
  const int li = lane & 15, lg = lane >> 4;

  STAGE_G(0,0) STAGE_G(0,1) STAGE_G(0,2) STAGE_G(0,3) STAGE_G(1,0) STAGE_G(1,1)
  asm volatile("s_waitcnt vmcnt(4)" ::: "memory");
  __builtin_amdgcn_s_barrier();

  #pragma unroll 1
  for (int tau = 0; tau < NTT; ++tau) {
    const int buf = tau & 1;
    bf16x8 a0[4], a1[4], aL0[4], aL1[4], bb0[4], bb1[4];
    #pragma unroll
    for (int m = 0; m < 4; ++m) LDA_(a0[m], m, 0);
    #pragma unroll
    for (int n = 0; n < 4; ++n) LDB_(bb0[n], n, 0);
    STAGE_G(tau+1, 2)
    PH_SYNC
    MFMA16(a0, bb0, 0)
    __builtin_amdgcn_s_barrier();
    #pragma unroll
    for (int m = 0; m < 4; ++m) LDA_(a1[m], m+4, 0);
    #pragma unroll
    for (int m = 0; m < 4; ++m) LDA_(aL0[m], m, 1);
    STAGE_G(tau+1, 3)
    PH_SYNC
    MFMA16(a1, bb0, 4)
    __builtin_amdgcn_s_barrier();
    #pragma unroll
    for (int m = 0; m < 4; ++m) LDA_(aL1[m], m+4, 1);
    #pragma unroll
    for (int n = 0; n < 4; ++n) LDB_(bb1[n], n, 1);
    PH_SYNC
    MFMA16(aL0, bb1, 0)
    __builtin_amdgcn_s_barrier();
    STAGE_G(tau+2, 0)
    STAGE_G(tau+2, 1)
    __builtin_amdgcn_sched_barrier(0);
    MFMA16(aL1, bb1, 4)
    if (tau < NTT-2) { asm volatile("s_waitcnt vmcnt(4)" ::: "memory"); }
    else             { asm volatile("s_waitcnt vmcnt(0)" ::: "memory"); }
    __builtin_amdgcn_s_barrier();
  }
}

// ---------------- persistent 256-wide pipeline (k_qkv; R6/R12-proven 151us core) ----------------
#define STAGE_P(tau_, part_)                                                              \
  if ((tau_) < NTP) {                                                                     \
    const int buf_ = (tau_) & 1, Tk_ = (tau_) & 7;                                        \
    const int ab_ = (part_) >> 1, hh_ = (part_) & 1;                                      \
    const unsigned short* src_ = ab_ ? B : A;                                             \
    const int row0_ = (ab_ ? ((tau_) >> 3)*256 : rowA0) + hh_*128;                        \
    _Pragma("unroll")                                                                     \
    for (int c_ = 0; c_ < 2; ++c_) {                                                      \
      int G_ = wid*128 + c_*64 + lane;                                                    \
      int r_ = G_ >> 3, g_ = G_ & 7;                                                      \
      int gsw_ = g_ ^ (r_ & 7);                                                           \
      __builtin_amdgcn_global_load_lds(                                                   \
        (const __attribute__((address_space(1))) unsigned int*)                           \
          ((const char*)src_ + (size_t)(row0_ + r_)*1024 + (size_t)Tk_*128 + gsw_*16),    \
        (__attribute__((address_space(3))) unsigned int*)                                 \
          ((char*)&L[buf_][ab_][hh_][0] + G_*16),                                         \
        16, 0, 0);                                                                        \
    }                                                                                     \
  }

template<int NB, class EPI>
__device__ __forceinline__ void gemm_persist(const unsigned short* __restrict__ A,
                                             const unsigned short* __restrict__ B,
                                             int rowA0,
                                             unsigned short (&L)[2][2][2][128*64],
                                             EPI&& epi) {
  constexpr int NTP = NB * 8;
  const int tid = threadIdx.x;
  const int lane = tid & 63, wid = tid >> 6;
  const int wr = wid >> 2, wc = wid & 3;
  const int li = lane & 15, lg = lane >> 4;

  STAGE_P(0,0) STAGE_P(0,1) STAGE_P(0,2) STAGE_P(0,3) STAGE_P(1,0) STAGE_P(1,1)
  asm volatile("s_waitcnt vmcnt(4)" ::: "memory");
  __builtin_amdgcn_s_barrier();

  f32x4 acc[8][4] = {};
  #pragma unroll 1
  for (int tau = 0; tau < NTP; ++tau) {
    const int buf = tau & 1;
    bf16x8 a0[4], a1[4], aL0[4], aL1[4], bb0[4], bb1[4];
    // ph0
    #pragma unroll
    for (int m = 0; m < 4; ++m) LDA_(a0[m], m, 0);
    #pragma unroll
    for (int n = 0; n < 4; ++n) LDB_(bb0[n], n, 0);
    STAGE_P(tau+1, 2)
    PH_SYNC
    MFMA16(a0, bb0, 0)
    __builtin_amdgcn_s_barrier();
    // ph1
    #pragma unroll
    for (int m = 0; m < 4; ++m) LDA_(a1[m], m+4, 0);
    #pragma unroll
    for (int m = 0; m < 4; ++m) LDA_(aL0[m], m, 1);
    STAGE_P(tau+1, 3)
    PH_SYNC
    MFMA16(a1, bb0, 4)
    __builtin_amdgcn_s_barrier();
    // ph2
    #pragma unroll
    for (int m = 0; m < 4; ++m) LDA_(aL1[m], m+4, 1);
    #pragma unroll
    for (int n = 0; n < 4; ++n) LDB_(bb1[n], n, 1);
    PH_SYNC
    MFMA16(aL0, bb1, 0)
    __builtin_amdgcn_s_barrier();
    // ph3
    STAGE_P(tau+2, 0)
    STAGE_P(tau+2, 1)
    __builtin_amdgcn_sched_barrier(0);
    MFMA16(aL1, bb1, 4)
    if (tau < NTP-2) { asm volatile("s_waitcnt vmcnt(4)" ::: "memory"); }
    else             { asm volatile("s_waitcnt vmcnt(0)" ::: "memory"); }
    __builtin_amdgcn_s_barrier();
    if ((tau & 7) == 7) {
      epi(tau >> 3, acc);
      #pragma unroll
      for (int m = 0; m < 8; ++m)
        #pragma unroll
        for (int n = 0; n < 4; ++n)
          acc[m][n] = (f32x4){0.f,0.f,0.f,0.f};
    }
  }
}

// ---------------- kernel 1: QKV GEMM + RMSNorm + RoPE + scatter (persistent) ----------------
__launch_bounds__(512)
__global__ void k_qkv(const unsigned short* __restrict__ A,    // x bf16 [65536][512], t = h*256+w
                      const unsigned short* __restrict__ B,    // w_qkv bf16 [1536][512]
                      const float* __restrict__ qnw, const float* __restrict__ knw,
                      const float2* __restrict__ rope,         // [256][32]
                      unsigned short* __restrict__ Qw,
                      unsigned short* __restrict__ Kw,
                      unsigned short* __restrict__ Vw) {
  __shared__ __align__(16) unsigned short L[2][2][2][128*64];  // 128 KiB
  const int bm = blockIdx.x;                                   // 256 blocks, one per A panel
  const int lane = threadIdx.x & 63, wid = threadIdx.x >> 6;
  const int wr = wid >> 2, wc = wid & 3;
  const int li = lane & 15, lg = lane >> 4;
  const int t0 = bm*256 + wr*128;
  const int hpos = bm;                  // t>>8 == bm for the whole block
  float2 cs[4]; float qn[4], kn[4];
  #pragma unroll
  for (int n = 0; n < 4; ++n) {
    int e = n*16 + li;
    cs[n] = rope[hpos*32 + (e >> 1)];
    qn[n] = qnw[e]; kn[n] = knw[e];
  }
  const bool odd = (li & 1) != 0;

  gemm_persist<6>(A, B, bm*256, L, [&](int j, f32x4 (&acc)[8][4]) {
    int d0 = j*256 + wc*64;             // 64-aligned => one (third, head) per wave
    int third = d0 >> 9;                // 0=q 1=k 2=v
    int nhh = (d0 >> 6) & 7;
    if (third == 2) {
      #pragma unroll
      for (int m = 0; m < 8; ++m)
        #pragma unroll
        for (int n = 0; n < 4; ++n)
          #pragma unroll
          for (int r = 0; r < 4; ++r) {
            int t = t0 + m*16 + lg*4 + r;
            int wI = t & 255;
            int e = n*16 + li;
            Vw[((size_t)(wI*8 + nhh)*256 + hpos)*64 + e] = f2bf(acc[m][n][r]);
          }
    } else {
      const float* nw = (third == 0) ? qn : kn;
      unsigned short* dst = (third == 0) ? Qw : Kw;
      const float qsc = (third == 0) ? 0.125f : 1.0f;   // fold hd^-0.5 into q
      #pragma unroll
      for (int m = 0; m < 8; ++m) {
        float rsg[4];
        #pragma unroll
        for (int r = 0; r < 4; ++r) {
          float p = 0.f;
          #pragma unroll
          for (int n = 0; n < 4; ++n) p += acc[m][n][r]*acc[m][n][r];
          #pragma unroll
          for (int d = 1; d < 16; d <<= 1) p += __shfl_xor(p, d, 64);   // head-dim reduce
          rsg[r] = rsqrtf(p*(1.0f/64.0f) + 1e-6f);
        }
        #pragma unroll
        for (int n = 0; n < 4; ++n)
          #pragma unroll
          for (int r = 0; r < 4; ++r) {
            float v = acc[m][n][r] * rsg[r] * nw[n];
            float pr = __shfl_xor(v, 1, 64);            // rope pair partner
            float res = odd ? (pr*cs[n].y + v*cs[n].x) : (v*cs[n].x - pr*cs[n].y);
            res *= qsc;
            int t = t0 + m*16 + lg*4 + r;
            int wI = t & 255;
            int e = n*16 + li;
            dst[((size_t)(wI*8 + nhh)*256 + hpos)*64 + e] = f2bf(res);
          }
      }
    }
  });
}

// ---------------- kernel 2: attention per (w, head) ----------------
// R13: K-fragments prefetched one kb ahead into kfr regs (T14 issue-early). The old code
// loaded kf immediately before the QK^T MFMAs that consume them -> hard vmcnt stall every
// kb. Now chunk kb+1's 8 b128 loads issue right after P-pack (where s[] dies, keeping
// peak VGPR flat) with ~600cy of cover (l-reduce + VT-write + PV). VT dbuf + 1 bar/kb
// (R12), V reg-staged (R11), T13 defer-max (R11) all retained.
__launch_bounds__(256, 2)
__global__ void k_attn(const unsigned short* __restrict__ Q,
                       const unsigned short* __restrict__ K,
                       const unsigned short* __restrict__ V,
                       unsigned short* __restrict__ O) {
  __shared__ __align__(16) unsigned short P_lds[4][64*64];   // 32 KB, per-wave, XOR-swizzled
  __shared__ __align__(16) unsigned short VT_lds[2][64*72];  // 18 KB, [buf][e][key+pad]
  int b = blockIdx.x;
  const unsigned short* Qb = Q + (size_t)b*SEQ*HD;
  const unsigned short* Kb = K + (size_t)b*SEQ*HD;
  const unsigned short* Vb = V + (size_t)b*SEQ*HD;           // [key][e]
  const int lane = threadIdx.x & 63, wid = threadIdx.x >> 6;
  const int li = lane & 15, lg = lane >> 4;
  const int q0 = wid*64;
  char* Pw = (char*)&P_lds[wid][0];

  // V chunk 0 -> regs -> VT[0]; then chunk 1 -> regs
  bf16x8 vrow[2];
  #pragma unroll
  for (int gi = 0; gi < 2; ++gi)
    vrow[gi] = *(const bf16x8*)(Vb + (size_t)lane*64 + (wid + gi*4)*8);
  #pragma unroll
  for (int gi = 0; gi < 2; ++gi) {
    int g = wid + gi*4;
    #pragma unroll
    for (int j = 0; j < 8; ++j)
      VT_lds[0][(g*8 + j)*72 + lane] = (unsigned short)vrow[gi][j];
  }
  #pragma unroll
  for (int gi = 0; gi < 2; ++gi)
    vrow[gi] = *(const bf16x8*)(Vb + (size_t)(64 + lane)*64 + (wid + gi*4)*8);

  // K chunk 0 -> regs (prefetch depth 1)
  bf16x8 kfr[2][4];
  #pragma unroll
  for (int kk = 0; kk < 2; ++kk)
    #pragma unroll
    for (int m = 0; m < 4; ++m)
      kfr[kk][m] = *(const bf16x8*)(Kb + (m*16 + li)*64 + kk*32 + lg*8);

  bf16x8 qf[4][2];                                           // Q resident in regs
  #pragma unroll
  for (int n = 0; n < 4; ++n)
    #pragma unroll
    for (int kk = 0; kk < 2; ++kk)
      qf[n][kk] = *(const bf16x8*)(Qb + (q0 + n*16 + li)*64 + kk*32 + lg*8);

  f32x4 oa[4][4] = {};
  float mrun[4], lrun[4];
  #pragma unroll
  for (int n = 0; n < 4; ++n) { mrun[n] = -1e30f; lrun[n] = 0.0f; }

  #pragma unroll 1
  for (int kb = 0; kb < 4; ++kb) {
    // S^T[key][q] = K @ Q^T  (kfr loaded one kb ago)
    f32x4 s[4][4] = {};
    #pragma unroll
    for (int kk = 0; kk < 2; ++kk) {
      __builtin_amdgcn_s_setprio(1);
      #pragma unroll
      for (int m = 0; m < 4; ++m)
        #pragma unroll
        for (int n = 0; n < 4; ++n)
          s[m][n] = __builtin_amdgcn_mfma_f32_16x16x32_bf16(kfr[kk][m], qf[n][kk], s[m][n], 0, 0, 0);
      __builtin_amdgcn_s_setprio(0);
    }
    // ---- online softmax with T13 defer-max ----
    float vmx[4];
    #pragma unroll
    for (int n = 0; n < 4; ++n) {
      float v = -1e30f;
      #pragma unroll
      for (int m = 0; m < 4; ++m)
        #pragma unroll
        for (int r = 0; r < 4; ++r) v = fmaxf(v, s[m][n][r]);
      v = fmaxf(v, __shfl_xor(v, 16, 64));
      v = fmaxf(v, __shfl_xor(v, 32, 64));
      vmx[n] = v;
    }
    float dmax = -1e30f;
    #pragma unroll
    for (int n = 0; n < 4; ++n) dmax = fmaxf(dmax, vmx[n] - mrun[n]);
    float mx[4];
    if (!__all(dmax <= 8.0f)) {                              // wave-uniform branch
      float al[4];
      #pragma unroll
      for (int n = 0; n < 4; ++n) {
        float mn = fmaxf(mrun[n], vmx[n]);
        al[n] = __expf(mrun[n] - mn);
        mrun[n] = mn; mx[n] = mn;
        lrun[n] *= al[n];
      }
      #pragma unroll
      for (int mp = 0; mp < 4; ++mp)
        #pragma unroll
        for (int r = 0; r < 4; ++r) {
          float a = __shfl(al[mp], lg*4 + r, 64);
          #pragma unroll
          for (int np = 0; np < 4; ++np) oa[mp][np][r] *= a;
        }
    } else {
      #pragma unroll
      for (int n = 0; n < 4; ++n) mx[n] = mrun[n];           // keep old max; P <= e^8
    }
    // ---- P = exp(S - mx), bf16-pack into per-wave swizzled P_lds ----
    float rs[4] = {0.f,0.f,0.f,0.f};
    #pragma unroll
    for (int m = 0; m < 4; ++m)
      #pragma unroll
      for (int n = 0; n < 4; ++n) {
        f32x4 sv = s[m][n];
        #pragma unroll
        for (int r = 0; r < 4; ++r) {
          float p = __expf(sv[r] - mx[n]);
          sv[r] = p; rs[n] += p;
        }
        unsigned lo = (unsigned)f2bf(sv[0]) | ((unsigned)f2bf(sv[1]) << 16);
        unsigned hi = (unsigned)f2bf(sv[2]) | ((unsigned)f2bf(sv[3]) << 16);
        uint2 pk; pk.x = lo; pk.y = hi;
        int q = n*16 + li;
        int off = (q*128 + (m*16 + lg*4)*2) ^ ((li & 7) << 4);   // XOR swizzle (T2)
        *(uint2*)(Pw + off) = pk;
      }
    // ---- prefetch K chunk kb+1 (s[] dead; ~600cy cover: reduce + VT + PV) ----
    if (kb < 3) {
      #pragma unroll
      for (int kk = 0; kk < 2; ++kk)
        #pragma unroll
        for (int m = 0; m < 4; ++m)
          kfr[kk][m] = *(const bf16x8*)(Kb + ((kb+1)*64 + m*16 + li)*64 + kk*32 + lg*8);
    }
    #pragma unroll
    for (int n = 0; n < 4; ++n) {
      rs[n] += __shfl_xor(rs[n], 16, 64);
      rs[n] += __shfl_xor(rs[n], 32, 64);
      lrun[n] += rs[n];
    }
    // ---- single sync point per kb ----
    asm volatile("s_waitcnt lgkmcnt(0)" ::: "memory");       // drain own PV(kb-1) reads + VT write
    __builtin_amdgcn_s_barrier();                            // publish VT[kb&1]
    if (kb < 3) {
      #pragma unroll
      for (int gi = 0; gi < 2; ++gi) {
        int g = wid + gi*4;
        #pragma unroll
        for (int j = 0; j < 8; ++j)
          VT_lds[(kb+1)&1][(g*8 + j)*72 + lane] = (unsigned short)vrow[gi][j];
      }
      if (kb < 2) {
        #pragma unroll
        for (int gi = 0; gi < 2; ++gi)
          vrow[gi] = *(const bf16x8*)(Vb + (size_t)((kb+2)*64 + lane)*64 + (wid + gi*4)*8);
      }
    }
    // PV: A = P (swizzled per-wave LDS), B = VT[kb&1][e][key] (b128)
    #pragma unroll
    for (int kk = 0; kk < 2; ++kk) {
      bf16x8 pf[4], vf[4];
      #pragma unroll
      for (int mp = 0; mp < 4; ++mp) {
        int q = mp*16 + li;
        int off = (q*128 + (kk*32 + lg*8)*2) ^ ((li & 7) << 4);
        pf[mp] = *(const bf16x8*)(Pw + off);
      }
      #pragma unroll
      for (int np = 0; np < 4; ++np)
        vf[np] = *(const bf16x8*)&VT_lds[kb&1][(np*16 + li)*72 + kk*32 + lg*8];
      __builtin_amdgcn_s_setprio(1);
      #pragma unroll
      for (int mp = 0; mp < 4; ++mp)
        #pragma unroll
        for (int np = 0; np < 4; ++np)
          oa[mp][np] = __builtin_amdgcn_mfma_f32_16x16x32_bf16(pf[mp], vf[np], oa[mp][np], 0, 0, 0);
      __builtin_amdgcn_s_setprio(0);
    }
  }
  // finalize: divide by l, store O rows t = h*256+w, cols head*64+e
  int wseq = b >> 3, whead = b & 7;
  #pragma unroll
  for (int mp = 0; mp < 4; ++mp)
    #pragma unroll
    for (int r = 0; r < 4; ++r) {
      float linv = 1.0f / __shfl(lrun[mp], lg*4 + r, 64);
      #pragma unroll
      for (int np = 0; np < 4; ++np) {
        int q = q0 + mp*16 + lg*4 + r;
        int e = np*16 + li;
        O[((size_t)q*WDIM + wseq)*CDIM + whead*HD + e] = f2bf(oa[mp][np][r] * linv);
      }
    }
}

// ---------------- kernel 3: out-proj GEMM + bias, fp32 out (non-persistent) ----------------
__launch_bounds__(512)
__global__ void k_proj(const unsigned short* __restrict__ A,   // O bf16 [65536][512]
                       const unsigned short* __restrict__ B,   // w_proj bf16 [512][512]
                       const float* __restrict__ bias,
                       float* __restrict__ out) {
  __shared__ __align__(16) unsigned short L[2][2][2][128*64];  // 128 KiB
  // T1: 512 = 8 XCD * 64
  int wg = (blockIdx.x & 7)*64 + (blockIdx.x >> 3);
  int bn = wg & 1, bm = wg >> 1;
  f32x4 acc[8][4] = {};
  gemm256(A, B, bm*256, bn*256, L, acc);

  const int lane = threadIdx.x & 63, wid = threadIdx.x >> 6;
  const int wr = wid >> 2, wc = wid & 3;
  const int li = lane & 15, lg = lane >> 4;
  int d0 = bn*256 + wc*64;
  int t0 = bm*256 + wr*128;
  float bi[4];
  #pragma unroll
  for (int n = 0; n < 4; ++n) bi[n] = bias[d0 + n*16 + li];
  #pragma unroll
  for (int m = 0; m < 8; ++m)
    #pragma unroll
    for (int n = 0; n < 4; ++n)
      #pragma unroll
      for (int r = 0; r < 4; ++r)
        out[(size_t)(t0 + m*16 + lg*4 + r)*CDIM + d0 + n*16 + li] = acc[m][n][r] + bi[n];
}

extern "C" void kernel_launch(void* const* d_in, const int* in_sizes, int n_in,
                              void* d_out, int out_size, void* d_ws, size_t ws_size,
                              hipStream_t stream) {
  (void)in_sizes; (void)n_in; (void)out_size; (void)ws_size;
  const float* x     = (const float*)d_in[0];
  const float* wqkv  = (const float*)d_in[1];
  const float* qnw   = (const float*)d_in[2];
  const float* knw   = (const float*)d_in[3];
  const float* wproj = (const float*)d_in[4];
  const float* bproj = (const float*)d_in[5];
  float* out = (float*)d_out;
  char* ws = (char*)d_ws;

  const size_t SZ_X = (size_t)NTOK*CDIM*2;                     // 64 MiB of bf16
  unsigned short* xb  = (unsigned short*)(ws);
  unsigned short* wqb = (unsigned short*)(ws + SZ_X);
  unsigned short* wpb = (unsigned short*)(ws + SZ_X + 1572864);
  float2*         rp  = (float2*)       (ws + SZ_X + 1572864 + 524288);
  unsigned short* Qw  = (unsigned short*)(ws + SZ_X + 1572864 + 524288 + 65536);
  unsigned short* Kw  = (unsigned short*)((char*)Qw + SZ_X);
  unsigned short* Vw  = (unsigned short*)((char*)Kw + SZ_X);
  unsigned short* Ow  = xb;   // x is dead after k_qkv; reuse its slot for attention output

  k_convert<<<dim3(2048), dim3(256), 0, stream>>>(x, wqkv, wproj, xb, wqb, wpb);
  k_rope   <<<dim3(32),   dim3(256), 0, stream>>>(rp);
  k_qkv    <<<dim3(256),  dim3(512), 0, stream>>>(xb, wqb, qnw, knw, rp, Qw, Kw, Vw);
  k_attn   <<<dim3(2048), dim3(256), 0, stream>>>(Qw, Kw, Vw, Ow);
  k_proj   <<<dim3(512),  dim3(512), 0, stream>>>(Ow, wpb, bproj, out);
}

// Round 14
// 315.218 us; speedup vs baseline: 1.1959x; 1.1959x over previous
//
#include <hip/hip_runtime.h>
#include <hip/hip_bf16.h>
#include <cstdint>
#include <cstddef>

#define SEQ 256
#define WDIM 256
#define CDIM 512
#define NHEAD 8
#define HD 64
#define NTOK (SEQ*WDIM)
#define NTT 8   // K=512 / BK=64 (non-persistent gemm256, k_proj)

typedef __attribute__((ext_vector_type(8))) short bf16x8;
typedef __attribute__((ext_vector_type(4))) float f32x4;

static __device__ __forceinline__ unsigned short f2bf(float f) {
  __hip_bfloat16 h = __float2bfloat16(f);
  return *reinterpret_cast<unsigned short*>(&h);
}

// ---------------- kernel 0: fp32 -> bf16 conversion (x + weights) ----------------
__global__ void k_convert(const float* __restrict__ x,
                          const float* __restrict__ wqkv,
                          const float* __restrict__ wproj,
                          unsigned short* __restrict__ xb,
                          unsigned short* __restrict__ wqb,
                          unsigned short* __restrict__ wpb) {
  const int NX = NTOK*CDIM/4, NQ = 3*CDIM*CDIM/4, NP = CDIM*CDIM/4;
  const int total = NX + NQ + NP;
  for (int i = blockIdx.x*blockDim.x + threadIdx.x; i < total; i += gridDim.x*blockDim.x) {
    const float4* s; unsigned short* d; int j;
    if (i < NX)           { s = (const float4*)x;     d = xb;  j = i; }
    else if (i < NX+NQ)   { s = (const float4*)wqkv;  d = wqb; j = i-NX; }
    else                  { s = (const float4*)wproj; d = wpb; j = i-NX-NQ; }
    float4 f = s[j];
    ushort4 o;
    o.x = f2bf(f.x); o.y = f2bf(f.y); o.z = f2bf(f.z); o.w = f2bf(f.w);
    ((ushort4*)d)[j] = o;
  }
}

// ---------------- kernel 0b: RoPE cos/sin table [256][32] ----------------
__global__ void k_rope(float2* __restrict__ tab) {
  int i = blockIdx.x*blockDim.x + threadIdx.x;
  if (i >= SEQ*32) return;
  int h = i >> 5, j = i & 31;
  float freq = expf(-12.0f + 12.0f*(float)j/31.0f);
  float ang = ((float)h/255.0f) * freq * 256.0f;
  tab[i] = make_float2(cosf(ang), sinf(ang));
}

// ================= shared GEMM macros =================
// LDS: L[buf][A=0/B=1][half][128x64 bf16], granule g of row r stored at g^(r&7) (T2).

#define LDA_(dst, m_, kk_)                                                                 \
  { int r_ = (m_)*16 + li;                                                                 \
    dst = *(const bf16x8*)((const char*)&L[buf][0][wr][0] + r_*128 + (((((kk_)*4)+lg) ^ (r_ & 7))<<4)); }
#define LDB_(dst, n_, kk_)                                                                 \
  { int r_ = (wc & 1)*64 + (n_)*16 + li;                                                   \
    dst = *(const bf16x8*)((const char*)&L[buf][1][wc>>1][0] + r_*128 + (((((kk_)*4)+lg) ^ (r_ & 7))<<4)); }

#define PH_SYNC                                            \
  __builtin_amdgcn_s_barrier();                            \
  asm volatile("s_waitcnt lgkmcnt(0)" ::: "memory");       \
  __builtin_amdgcn_sched_barrier(0);

#define MFMA16(afr, bfr, mo)                                                               \
  __builtin_amdgcn_s_setprio(1);                                                          \
  _Pragma("unroll")                                                                        \
  for (int m = 0; m < 4; ++m)                                                              \
    _Pragma("unroll")                                                                      \
    for (int n = 0; n < 4; ++n)                                                            \
      acc[m+(mo)][n] = __builtin_amdgcn_mfma_f32_16x16x32_bf16(afr[m], bfr[n], acc[m+(mo)][n], 0, 0, 0); \
  __builtin_amdgcn_s_setprio(0);

// ---------------- non-persistent 256x256 4-phase core (k_proj; R7/R9-proven) ----------------
#define STAGE_G(tau_, part_)                                                              \
  if ((tau_) < NTT) {                                                                     \
    const int buf_ = (tau_) & 1;                                                          \
    const int ab_ = (part_) >> 1, hh_ = (part_) & 1;                                      \
    const unsigned short* src_ = ab_ ? B : A;                                             \
    const int row0_ = (ab_ ? rowB0 : rowA0) + hh_*128;                                    \
    _Pragma("unroll")                                                                     \
    for (int c_ = 0; c_ < 2; ++c_) {                                                      \
      int G_ = wid*128 + c_*64 + lane;                                                    \
      int r_ = G_ >> 3, g_ = G_ & 7;                                                      \
      int gsw_ = g_ ^ (r_ & 7);                                                           \
      __builtin_amdgcn_global_load_lds(                                                   \
        (const __attribute__((address_space(1))) unsigned int*)                           \
          ((const char*)src_ + (size_t)(row0_ + r_)*1024 + (size_t)(tau_)*128 + gsw_*16), \
        (__attribute__((address_space(3))) unsigned int*)                                 \
          ((char*)&L[buf_][ab_][hh_][0] + G_*16),                                         \
        16, 0, 0);                                                                        \
    }                                                                                     \
  }

__device__ __forceinline__ void gemm256(const unsigned short* __restrict__ A,
                                        const unsigned short* __restrict__ B,
                                        int rowA0, int rowB0,
                                        unsigned short (&L)[2][2][2][128*64],
                                        f32x4 (&acc)[8][4]) {
  const int tid = threadIdx.x;
  const int lane = tid & 63, wid = tid >> 6;
  const int wr = wid >> 2, wc = wid & 3;
  const int li = lane & 15, lg = lane >> 4;

  STAGE_G(0,0) STAGE_G(0,1) STAGE_G(0,2) STAGE_G(0,3) STAGE_G(1,0) STAGE_G(1,1)
  asm volatile("s_waitcnt vmcnt(4)" ::: "memory");
  __builtin_amdgcn_s_barrier();

  #pragma unroll 1
  for (int tau = 0; tau < NTT; ++tau) {
    const int buf = tau & 1;
    bf16x8 a0[4], a1[4], aL0[4], aL1[4], bb0[4], bb1[4];
    #pragma unroll
    for (int m = 0; m < 4; ++m) LDA_(a0[m], m, 0);
    #pragma unroll
    for (int n = 0; n < 4; ++n) LDB_(bb0[n], n, 0);
    STAGE_G(tau+1, 2)
    PH_SYNC
    MFMA16(a0, bb0, 0)
    __builtin_amdgcn_s_barrier();
    #pragma unroll
    for (int m = 0; m < 4; ++m) LDA_(a1[m], m+4, 0);
    #pragma unroll
    for (int m = 0; m < 4; ++m) LDA_(aL0[m], m, 1);
    STAGE_G(tau+1, 3)
    PH_SYNC
    MFMA16(a1, bb0, 4)
    __builtin_amdgcn_s_barrier();
    #pragma unroll
    for (int m = 0; m < 4; ++m) LDA_(aL1[m], m+4, 1);
    #pragma unroll
    for (int n = 0; n < 4; ++n) LDB_(bb1[n], n, 1);
    PH_SYNC
    MFMA16(aL0, bb1, 0)
    __builtin_amdgcn_s_barrier();
    STAGE_G(tau+2, 0)
    STAGE_G(tau+2, 1)
    __builtin_amdgcn_sched_barrier(0);
    MFMA16(aL1, bb1, 4)
    if (tau < NTT-2) { asm volatile("s_waitcnt vmcnt(4)" ::: "memory"); }
    else             { asm volatile("s_waitcnt vmcnt(0)" ::: "memory"); }
    __builtin_amdgcn_s_barrier();
  }
}

// ---------------- persistent 256-wide pipeline (k_qkv; R6/R12-proven 151us core) ----------------
#define STAGE_P(tau_, part_)                                                              \
  if ((tau_) < NTP) {                                                                     \
    const int buf_ = (tau_) & 1, Tk_ = (tau_) & 7;                                        \
    const int ab_ = (part_) >> 1, hh_ = (part_) & 1;                                      \
    const unsigned short* src_ = ab_ ? B : A;                                             \
    const int row0_ = (ab_ ? ((tau_) >> 3)*256 : rowA0) + hh_*128;                        \
    _Pragma("unroll")                                                                     \
    for (int c_ = 0; c_ < 2; ++c_) {                                                      \
      int G_ = wid*128 + c_*64 + lane;                                                    \
      int r_ = G_ >> 3, g_ = G_ & 7;                                                      \
      int gsw_ = g_ ^ (r_ & 7);                                                           \
      __builtin_amdgcn_global_load_lds(                                                   \
        (const __attribute__((address_space(1))) unsigned int*)                           \
          ((const char*)src_ + (size_t)(row0_ + r_)*1024 + (size_t)Tk_*128 + gsw_*16),    \
        (__attribute__((address_space(3))) unsigned int*)                                 \
          ((char*)&L[buf_][ab_][hh_][0] + G_*16),                                         \
        16, 0, 0);                                                                        \
    }                                                                                     \
  }

template<int NB, class EPI>
__device__ __forceinline__ void gemm_persist(const unsigned short* __restrict__ A,
                                             const unsigned short* __restrict__ B,
                                             int rowA0,
                                             unsigned short (&L)[2][2][2][128*64],
                                             EPI&& epi) {
  constexpr int NTP = NB * 8;
  const int tid = threadIdx.x;
  const int lane = tid & 63, wid = tid >> 6;
  const int wr = wid >> 2, wc = wid & 3;
  const int li = lane & 15, lg = lane >> 4;

  STAGE_P(0,0) STAGE_P(0,1) STAGE_P(0,2) STAGE_P(0,3) STAGE_P(1,0) STAGE_P(1,1)
  asm volatile("s_waitcnt vmcnt(4)" ::: "memory");
  __builtin_amdgcn_s_barrier();

  f32x4 acc[8][4] = {};
  #pragma unroll 1
  for (int tau = 0; tau < NTP; ++tau) {
    const int buf = tau & 1;
    bf16x8 a0[4], a1[4], aL0[4], aL1[4], bb0[4], bb1[4];
    // ph0
    #pragma unroll
    for (int m = 0; m < 4; ++m) LDA_(a0[m], m, 0);
    #pragma unroll
    for (int n = 0; n < 4; ++n) LDB_(bb0[n], n, 0);
    STAGE_P(tau+1, 2)
    PH_SYNC
    MFMA16(a0, bb0, 0)
    __builtin_amdgcn_s_barrier();
    // ph1
    #pragma unroll
    for (int m = 0; m < 4; ++m) LDA_(a1[m], m+4, 0);
    #pragma unroll
    for (int m = 0; m < 4; ++m) LDA_(aL0[m], m, 1);
    STAGE_P(tau+1, 3)
    PH_SYNC
    MFMA16(a1, bb0, 4)
    __builtin_amdgcn_s_barrier();
    // ph2
    #pragma unroll
    for (int m = 0; m < 4; ++m) LDA_(aL1[m], m+4, 1);
    #pragma unroll
    for (int n = 0; n < 4; ++n) LDB_(bb1[n], n, 1);
    PH_SYNC
    MFMA16(aL0, bb1, 0)
    __builtin_amdgcn_s_barrier();
    // ph3
    STAGE_P(tau+2, 0)
    STAGE_P(tau+2, 1)
    __builtin_amdgcn_sched_barrier(0);
    MFMA16(aL1, bb1, 4)
    if (tau < NTP-2) { asm volatile("s_waitcnt vmcnt(4)" ::: "memory"); }
    else             { asm volatile("s_waitcnt vmcnt(0)" ::: "memory"); }
    __builtin_amdgcn_s_barrier();
    if ((tau & 7) == 7) {
      epi(tau >> 3, acc);
      #pragma unroll
      for (int m = 0; m < 8; ++m)
        #pragma unroll
        for (int n = 0; n < 4; ++n)
          acc[m][n] = (f32x4){0.f,0.f,0.f,0.f};
    }
  }
}

// ---------------- kernel 1: QKV GEMM + RMSNorm + RoPE + scatter (persistent) ----------------
__launch_bounds__(512)
__global__ void k_qkv(const unsigned short* __restrict__ A,    // x bf16 [65536][512], t = h*256+w
                      const unsigned short* __restrict__ B,    // w_qkv bf16 [1536][512]
                      const float* __restrict__ qnw, const float* __restrict__ knw,
                      const float2* __restrict__ rope,         // [256][32]
                      unsigned short* __restrict__ Qw,
                      unsigned short* __restrict__ Kw,
                      unsigned short* __restrict__ Vw) {
  __shared__ __align__(16) unsigned short L[2][2][2][128*64];  // 128 KiB
  const int bm = blockIdx.x;                                   // 256 blocks, one per A panel
  const int lane = threadIdx.x & 63, wid = threadIdx.x >> 6;
  const int wr = wid >> 2, wc = wid & 3;
  const int li = lane & 15, lg = lane >> 4;
  const int t0 = bm*256 + wr*128;
  const int hpos = bm;                  // t>>8 == bm for the whole block
  float2 cs[4]; float qn[4], kn[4];
  #pragma unroll
  for (int n = 0; n < 4; ++n) {
    int e = n*16 + li;
    cs[n] = rope[hpos*32 + (e >> 1)];
    qn[n] = qnw[e]; kn[n] = knw[e];
  }
  const bool odd = (li & 1) != 0;

  gemm_persist<6>(A, B, bm*256, L, [&](int j, f32x4 (&acc)[8][4]) {
    int d0 = j*256 + wc*64;             // 64-aligned => one (third, head) per wave
    int third = d0 >> 9;                // 0=q 1=k 2=v
    int nhh = (d0 >> 6) & 7;
    if (third == 2) {
      #pragma unroll
      for (int m = 0; m < 8; ++m)
        #pragma unroll
        for (int n = 0; n < 4; ++n)
          #pragma unroll
          for (int r = 0; r < 4; ++r) {
            int t = t0 + m*16 + lg*4 + r;
            int wI = t & 255;
            int e = n*16 + li;
            Vw[((size_t)(wI*8 + nhh)*256 + hpos)*64 + e] = f2bf(acc[m][n][r]);
          }
    } else {
      const float* nw = (third == 0) ? qn : kn;
      unsigned short* dst = (third == 0) ? Qw : Kw;
      const float qsc = (third == 0) ? 0.125f : 1.0f;   // fold hd^-0.5 into q
      #pragma unroll
      for (int m = 0; m < 8; ++m) {
        float rsg[4];
        #pragma unroll
        for (int r = 0; r < 4; ++r) {
          float p = 0.f;
          #pragma unroll
          for (int n = 0; n < 4; ++n) p += acc[m][n][r]*acc[m][n][r];
          #pragma unroll
          for (int d = 1; d < 16; d <<= 1) p += __shfl_xor(p, d, 64);   // head-dim reduce
          rsg[r] = rsqrtf(p*(1.0f/64.0f) + 1e-6f);
        }
        #pragma unroll
        for (int n = 0; n < 4; ++n)
          #pragma unroll
          for (int r = 0; r < 4; ++r) {
            float v = acc[m][n][r] * rsg[r] * nw[n];
            float pr = __shfl_xor(v, 1, 64);            // rope pair partner
            float res = odd ? (pr*cs[n].y + v*cs[n].x) : (v*cs[n].x - pr*cs[n].y);
            res *= qsc;
            int t = t0 + m*16 + lg*4 + r;
            int wI = t & 255;
            int e = n*16 + li;
            dst[((size_t)(wI*8 + nhh)*256 + hpos)*64 + e] = f2bf(res);
          }
      }
    }
  });
}

// ---------------- kernel 2: attention per (w, head) ----------------
// R14 = R12 state (proven) + zero-risk hoist: both kk-groups' K loads issued before the
// first QK^T MFMA in the same basic block (no loop-carried registers — the R13 lesson:
// carrying kfr across the barrier/loop edge caused a 2x regression via regalloc).
// VT dbuf + 1 bar/kb, V reg-staged, T13 defer-max retained.
__launch_bounds__(256, 2)
__global__ void k_attn(const unsigned short* __restrict__ Q,
                       const unsigned short* __restrict__ K,
                       const unsigned short* __restrict__ V,
                       unsigned short* __restrict__ O) {
  __shared__ __align__(16) unsigned short P_lds[4][64*64];   // 32 KB, per-wave, XOR-swizzled
  __shared__ __align__(16) unsigned short VT_lds[2][64*72];  // 18 KB, [buf][e][key+pad]
  int b = blockIdx.x;
  const unsigned short* Qb = Q + (size_t)b*SEQ*HD;
  const unsigned short* Kb = K + (size_t)b*SEQ*HD;
  const unsigned short* Vb = V + (size_t)b*SEQ*HD;           // [key][e]
  const int lane = threadIdx.x & 63, wid = threadIdx.x >> 6;
  const int li = lane & 15, lg = lane >> 4;
  const int q0 = wid*64;
  char* Pw = (char*)&P_lds[wid][0];

  // V chunk 0 -> regs -> VT[0]; then chunk 1 -> regs
  bf16x8 vrow[2];
  #pragma unroll
  for (int gi = 0; gi < 2; ++gi)
    vrow[gi] = *(const bf16x8*)(Vb + (size_t)lane*64 + (wid + gi*4)*8);
  #pragma unroll
  for (int gi = 0; gi < 2; ++gi) {
    int g = wid + gi*4;
    #pragma unroll
    for (int j = 0; j < 8; ++j)
      VT_lds[0][(g*8 + j)*72 + lane] = (unsigned short)vrow[gi][j];
  }
  #pragma unroll
  for (int gi = 0; gi < 2; ++gi)
    vrow[gi] = *(const bf16x8*)(Vb + (size_t)(64 + lane)*64 + (wid + gi*4)*8);

  bf16x8 qf[4][2];                                           // Q resident in regs
  #pragma unroll
  for (int n = 0; n < 4; ++n)
    #pragma unroll
    for (int kk = 0; kk < 2; ++kk)
      qf[n][kk] = *(const bf16x8*)(Qb + (q0 + n*16 + li)*64 + kk*32 + lg*8);

  f32x4 oa[4][4] = {};
  float mrun[4], lrun[4];
  #pragma unroll
  for (int n = 0; n < 4; ++n) { mrun[n] = -1e30f; lrun[n] = 0.0f; }

  #pragma unroll 1
  for (int kb = 0; kb < 4; ++kb) {
    int key0 = kb*64;
    // S^T[key][q] = K @ Q^T — all 8 K loads issued before the first MFMA (same block)
    bf16x8 kf[2][4];
    #pragma unroll
    for (int kk = 0; kk < 2; ++kk)
      #pragma unroll
      for (int m = 0; m < 4; ++m)
        kf[kk][m] = *(const bf16x8*)(Kb + (key0 + m*16 + li)*64 + kk*32 + lg*8);
    f32x4 s[4][4] = {};
    #pragma unroll
    for (int kk = 0; kk < 2; ++kk) {
      __builtin_amdgcn_s_setprio(1);
      #pragma unroll
      for (int m = 0; m < 4; ++m)
        #pragma unroll
        for (int n = 0; n < 4; ++n)
          s[m][n] = __builtin_amdgcn_mfma_f32_16x16x32_bf16(kf[kk][m], qf[n][kk], s[m][n], 0, 0, 0);
      __builtin_amdgcn_s_setprio(0);
    }
    // ---- online softmax with T13 defer-max ----
    float vmx[4];
    #pragma unroll
    for (int n = 0; n < 4; ++n) {
      float v = -1e30f;
      #pragma unroll
      for (int m = 0; m < 4; ++m)
        #pragma unroll
        for (int r = 0; r < 4; ++r) v = fmaxf(v, s[m][n][r]);
      v = fmaxf(v, __shfl_xor(v, 16, 64));
      v = fmaxf(v, __shfl_xor(v, 32, 64));
      vmx[n] = v;
    }
    float dmax = -1e30f;
    #pragma unroll
    for (int n = 0; n < 4; ++n) dmax = fmaxf(dmax, vmx[n] - mrun[n]);
    float mx[4];
    if (!__all(dmax <= 8.0f)) {                              // wave-uniform branch
      float al[4];
      #pragma unroll
      for (int n = 0; n < 4; ++n) {
        float mn = fmaxf(mrun[n], vmx[n]);
        al[n] = __expf(mrun[n] - mn);
        mrun[n] = mn; mx[n] = mn;
        lrun[n] *= al[n];
      }
      #pragma unroll
      for (int mp = 0; mp < 4; ++mp)
        #pragma unroll
        for (int r = 0; r < 4; ++r) {
          float a = __shfl(al[mp], lg*4 + r, 64);
          #pragma unroll
          for (int np = 0; np < 4; ++np) oa[mp][np][r] *= a;
        }
    } else {
      #pragma unroll
      for (int n = 0; n < 4; ++n) mx[n] = mrun[n];           // keep old max; P <= e^8
    }
    // ---- P = exp(S - mx), bf16-pack into per-wave swizzled P_lds ----
    float rs[4] = {0.f,0.f,0.f,0.f};
    #pragma unroll
    for (int m = 0; m < 4; ++m)
      #pragma unroll
      for (int n = 0; n < 4; ++n) {
        f32x4 sv = s[m][n];
        #pragma unroll
        for (int r = 0; r < 4; ++r) {
          float p = __expf(sv[r] - mx[n]);
          sv[r] = p; rs[n] += p;
        }
        unsigned lo = (unsigned)f2bf(sv[0]) | ((unsigned)f2bf(sv[1]) << 16);
        unsigned hi = (unsigned)f2bf(sv[2]) | ((unsigned)f2bf(sv[3]) << 16);
        uint2 pk; pk.x = lo; pk.y = hi;
        int q = n*16 + li;
        int off = (q*128 + (m*16 + lg*4)*2) ^ ((li & 7) << 4);   // XOR swizzle (T2)
        *(uint2*)(Pw + off) = pk;
      }
    #pragma unroll
    for (int n = 0; n < 4; ++n) {
      rs[n] += __shfl_xor(rs[n], 16, 64);
      rs[n] += __shfl_xor(rs[n], 32, 64);
      lrun[n] += rs[n];
    }
    // ---- single sync point per kb ----
    asm volatile("s_waitcnt lgkmcnt(0)" ::: "memory");       // drain own PV(kb-1) reads + VT write
    __builtin_amdgcn_s_barrier();                            // publish VT[kb&1]
    if (kb < 3) {
      #pragma unroll
      for (int gi = 0; gi < 2; ++gi) {
        int g = wid + gi*4;
        #pragma unroll
        for (int j = 0; j < 8; ++j)
          VT_lds[(kb+1)&1][(g*8 + j)*72 + lane] = (unsigned short)vrow[gi][j];
      }
      if (kb < 2) {
        #pragma unroll
        for (int gi = 0; gi < 2; ++gi)
          vrow[gi] = *(const bf16x8*)(Vb + (size_t)((kb+2)*64 + lane)*64 + (wid + gi*4)*8);
      }
    }
    // PV: A = P (swizzled per-wave LDS), B = VT[kb&1][e][key] (b128)
    #pragma unroll
    for (int kk = 0; kk < 2; ++kk) {
      bf16x8 pf[4], vf[4];
      #pragma unroll
      for (int mp = 0; mp < 4; ++mp) {
        int q = mp*16 + li;
        int off = (q*128 + (kk*32 + lg*8)*2) ^ ((li & 7) << 4);
        pf[mp] = *(const bf16x8*)(Pw + off);
      }
      #pragma unroll
      for (int np = 0; np < 4; ++np)
        vf[np] = *(const bf16x8*)&VT_lds[kb&1][(np*16 + li)*72 + kk*32 + lg*8];
      __builtin_amdgcn_s_setprio(1);
      #pragma unroll
      for (int mp = 0; mp < 4; ++mp)
        #pragma unroll
        for (int np = 0; np < 4; ++np)
          oa[mp][np] = __builtin_amdgcn_mfma_f32_16x16x32_bf16(pf[mp], vf[np], oa[mp][np], 0, 0, 0);
      __builtin_amdgcn_s_setprio(0);
    }
  }
  // finalize: divide by l, store O rows t = h*256+w, cols head*64+e
  int wseq = b >> 3, whead = b & 7;
  #pragma unroll
  for (int mp = 0; mp < 4; ++mp)
    #pragma unroll
    for (int r = 0; r < 4; ++r) {
      float linv = 1.0f / __shfl(lrun[mp], lg*4 + r, 64);
      #pragma unroll
      for (int np = 0; np < 4; ++np) {
        int q = q0 + mp*16 + lg*4 + r;
        int e = np*16 + li;
        O[((size_t)q*WDIM + wseq)*CDIM + whead*HD + e] = f2bf(oa[mp][np][r] * linv);
      }
    }
}

// ---------------- kernel 3: out-proj GEMM + bias, fp32 out (non-persistent) ----------------
__launch_bounds__(512)
__global__ void k_proj(const unsigned short* __restrict__ A,   // O bf16 [65536][512]
                       const unsigned short* __restrict__ B,   // w_proj bf16 [512][512]
                       const float* __restrict__ bias,
                       float* __restrict__ out) {
  __shared__ __align__(16) unsigned short L[2][2][2][128*64];  // 128 KiB
  // T1: 512 = 8 XCD * 64
  int wg = (blockIdx.x & 7)*64 + (blockIdx.x >> 3);
  int bn = wg & 1, bm = wg >> 1;
  f32x4 acc[8][4] = {};
  gemm256(A, B, bm*256, bn*256, L, acc);

  const int lane = threadIdx.x & 63, wid = threadIdx.x >> 6;
  const int wr = wid >> 2, wc = wid & 3;
  const int li = lane & 15, lg = lane >> 4;
  int d0 = bn*256 + wc*64;
  int t0 = bm*256 + wr*128;
  float bi[4];
  #pragma unroll
  for (int n = 0; n < 4; ++n) bi[n] = bias[d0 + n*16 + li];
  #pragma unroll
  for (int m = 0; m < 8; ++m)
    #pragma unroll
    for (int n = 0; n < 4; ++n)
      #pragma unroll
      for (int r = 0; r < 4; ++r)
        out[(size_t)(t0 + m*16 + lg*4 + r)*CDIM + d0 + n*16 + li] = acc[m][n][r] + bi[n];
}

extern "C" void kernel_launch(void* const* d_in, const int* in_sizes, int n_in,
                              void* d_out, int out_size, void* d_ws, size_t ws_size,
                              hipStream_t stream) {
  (void)in_sizes; (void)n_in; (void)out_size; (void)ws_size;
  const float* x     = (const float*)d_in[0];
  const float* wqkv  = (const float*)d_in[1];
  const float* qnw   = (const float*)d_in[2];
  const float* knw   = (const float*)d_in[3];
  const float* wproj = (const float*)d_in[4];
  const float* bproj = (const float*)d_in[5];
  float* out = (float*)d_out;
  char* ws = (char*)d_ws;

  const size_t SZ_X = (size_t)NTOK*CDIM*2;                     // 64 MiB of bf16
  unsigned short* xb  = (unsigned short*)(ws);
  unsigned short* wqb = (unsigned short*)(ws + SZ_X);
  unsigned short* wpb = (unsigned short*)(ws + SZ_X + 1572864);
  float2*         rp  = (float2*)       (ws + SZ_X + 1572864 + 524288);
  unsigned short* Qw  = (unsigned short*)(ws + SZ_X + 1572864 + 524288 + 65536);
  unsigned short* Kw  = (unsigned short*)((char*)Qw + SZ_X);
  unsigned short* Vw  = (unsigned short*)((char*)Kw + SZ_X);
  unsigned short* Ow  = xb;   // x is dead after k_qkv; reuse its slot for attention output

  k_convert<<<dim3(2048), dim3(256), 0, stream>>>(x, wqkv, wproj, xb, wqb, wpb);
  k_rope   <<<dim3(32),   dim3(256), 0, stream>>>(rp);
  k_qkv    <<<dim3(256),  dim3(512), 0, stream>>>(xb, wqb, qnw, knw, rp, Qw, Kw, Vw);
  k_attn   <<<dim3(2048), dim3(256), 0, stream>>>(Qw, Kw, Vw, Ow);
  k_proj   <<<dim3(512),  dim3(512), 0, stream>>>(Ow, wpb, bproj, out);
}